// Round 3
// baseline (49.249 us; speedup 1.0000x reference)
//
#include <hip/hip_runtime.h>
#include <math.h>

#define B_    512
#define C_    10
#define HW_   4096
#define NT    512       // 8 waves/block, 1 block per sample, 8 px/thread
#define NBMP  313       // ceil(10^4 / 32) presence-bitmap words

typedef float f4v __attribute__((ext_vector_type(4)));
typedef int   i4v __attribute__((ext_vector_type(4)));

__device__ __forceinline__ f4v ntld_f4(const float* p) {
    return __builtin_nontemporal_load((const f4v*)p);   // single-use stream: bypass L2
}
__device__ __forceinline__ i4v ntld_i4(const int* p) {
    return __builtin_nontemporal_load((const i4v*)p);
}
__device__ __forceinline__ float wave_sum_f(float v) {
#pragma unroll
    for (int off = 32; off > 0; off >>= 1) v += __shfl_xor(v, off, 64);
    return v;
}
// Block-wide sum over NT threads; valid on tid==0 only.
__device__ __forceinline__ float block_sum(float v, volatile float* sp, int tid) {
    v = wave_sum_f(v);
    __syncthreads();
    if ((tid & 63) == 0) sp[tid >> 6] = v;
    __syncthreads();
    float s = 0.f;
    if (tid == 0) {
#pragma unroll
        for (int i = 0; i < NT / 64; ++i) s += sp[i];
    }
    return s;
}
__device__ __forceinline__ float agld(const float* p) {   // cross-XCD-safe load
    return __hip_atomic_load(p, __ATOMIC_RELAXED, __HIP_MEMORY_SCOPE_AGENT);
}

__global__ __launch_bounds__(NT, 4) void loss_all(
    const float* __restrict__ pred, const int* __restrict__ tgt,
    const int* __restrict__ inp, const float* __restrict__ strat,
    float* __restrict__ ws, float* __restrict__ out,
    unsigned int* __restrict__ ticket)
{
    const int b   = blockIdx.x;
    const int tid = threadIdx.x;

    __shared__ unsigned int s_pred32[HW_ / 4];   // packed pred_idx bytes
    __shared__ unsigned int s_bmp[NBMP];
    __shared__ float        s_red[8][5];
    __shared__ unsigned int s_cmask;
    __shared__ int          s_last;

    if (tid < NBMP) s_bmp[tid] = 0u;
    if (tid == 0) s_cmask = 0u;

    const float* pb = pred + (size_t)b * (C_ * HW_);

    float focal = 0.f;
    unsigned cmask = 0u;
    int eqc = 0, dfc = 0;

#pragma unroll
    for (int k = 0; k < 2; ++k) {
        const int p = (k * NT + tid) * 4;           // 4 px per round
        const i4v t4 = ntld_i4(tgt + b * HW_ + p);
        const i4v i4 = ntld_i4(inp + b * HW_ + p);
        float x[C_][4];
#pragma unroll
        for (int c = 0; c < C_; ++c) {
            const f4v v = ntld_f4(pb + c * HW_ + p);
            x[c][0] = v.x; x[c][1] = v.y; x[c][2] = v.z; x[c][3] = v.w;
        }
        unsigned pack = 0u;
#pragma unroll
        for (int e = 0; e < 4; ++e) {
            const int t  = (e == 0) ? t4.x : (e == 1) ? t4.y : (e == 2) ? t4.z : t4.w;
            const int iv = (e == 0) ? i4.x : (e == 1) ? i4.y : (e == 2) ? i4.z : i4.w;
            cmask |= 1u << t;
            float mx = x[0][e]; int am = 0;
#pragma unroll
            for (int c = 1; c < C_; ++c)
                if (x[c][e] > mx) { mx = x[c][e]; am = c; }   // strict >: first max
            float se = 0.f, xt = 0.f;
#pragma unroll
            for (int c = 0; c < C_; ++c) {
                se += __expf(x[c][e] - mx);
                if (c == t) xt = x[c][e];
            }
            const float ce = (mx + __logf(se)) - xt;   // -log_softmax[target]
            const float pt = __expf(-ce);
            const float om = 1.f - pt;
            focal += om * om * ce;
            eqc += (am == t);
            dfc += (am != iv);
            pack |= (unsigned)am << (8 * e);
        }
        s_pred32[k * NT + tid] = pack;   // lane i -> dword i, conflict-free
    }

    float cre = 0.f;
    if (tid < 128) {
        const float sv = strat[b * 128 + tid];
        cre = 1.f / (1.f + __expf(-sv));
    }

    __syncthreads();   // s_pred32 complete, s_bmp zeroed

    // 2x2-window diversity over packed dwords: 63 rows x 16 dwords = 1008 slots
    for (int idx = tid; idx < 1008; idx += NT) {
        const int c4 = (idx & 15) << 2;            // 0,4,...,60
        const unsigned w0 = s_pred32[idx];
        const unsigned w1 = s_pred32[idx + 16];
        const unsigned n0 = (c4 < 60) ? s_pred32[idx + 1]  : 0u;
        const unsigned n1 = (c4 < 60) ? s_pred32[idx + 17] : 0u;
        const unsigned a0 =  w0        & 0xffu, a1 = (w0 >>  8) & 0xffu,
                       a2 = (w0 >> 16) & 0xffu, a3 = (w0 >> 24) & 0xffu,
                       a4 =  n0        & 0xffu;
        const unsigned b0 =  w1        & 0xffu, b1 = (w1 >>  8) & 0xffu,
                       b2 = (w1 >> 16) & 0xffu, b3 = (w1 >> 24) & 0xffu,
                       b4 =  n1        & 0xffu;
        unsigned code;
        code = a0 * 1000u + a1 * 100u + b0 * 10u + b1;
        atomicOr(&s_bmp[code >> 5], 1u << (code & 31u));
        code = a1 * 1000u + a2 * 100u + b1 * 10u + b2;
        atomicOr(&s_bmp[code >> 5], 1u << (code & 31u));
        code = a2 * 1000u + a3 * 100u + b2 * 10u + b3;
        atomicOr(&s_bmp[code >> 5], 1u << (code & 31u));
        if (c4 < 60) {
            code = a3 * 1000u + a4 * 100u + b3 * 10u + b4;
            atomicOr(&s_bmp[code >> 5], 1u << (code & 31u));
        }
    }
    __syncthreads();

    const int nu = (tid < NBMP) ? __popc(s_bmp[tid]) : 0;

    // per-sample reductions (8 waves): 5 shfl-reduces + colmask OR
    const float rf = wave_sum_f(focal);
    const float re = wave_sum_f((float)eqc);
    const float rd = wave_sum_f((float)dfc);
    const float rc = wave_sum_f(cre);
    const float rn = wave_sum_f((float)nu);
#pragma unroll
    for (int off = 32; off > 0; off >>= 1)
        cmask |= (unsigned)__shfl_xor((int)cmask, off, 64);

    const int wv = tid >> 6;
    if ((tid & 63) == 0) {
        s_red[wv][0] = rf; s_red[wv][1] = re; s_red[wv][2] = rd;
        s_red[wv][3] = rc; s_red[wv][4] = rn;
        atomicOr(&s_cmask, cmask);
    }
    __syncthreads();
    if (tid == 0) {
        float F = 0.f, E = 0.f, D = 0.f, CR = 0.f, NU = 0.f;
#pragma unroll
        for (int i = 0; i < 8; ++i) {
            F += s_red[i][0]; E += s_red[i][1]; D += s_red[i][2];
            CR += s_red[i][3]; NU += s_red[i][4];
        }
        const int uc = __popc(s_cmask);
        const float sw = (uc > 3) ? 1.2f : 1.0f;   // strategic weight
        ws[0 * B_ + b] = F * sw;
        ws[1 * B_ + b] = E;                               // intersection
        ws[2 * B_ + b] = (E == 4096.f) ? 1.f : 0.f;       // exact strict
        ws[3 * B_ + b] = (D == 0.f) ? 1.f : 0.f;          // copy flag
        ws[4 * B_ + b] = NU;                              // unique 2x2 codes
        ws[5 * B_ + b] = CR;                              // sigmoid sum
        __threadfence();                                  // release partials
        const unsigned old = atomicAdd(ticket, 1u);       // device-scope RMW
        s_last = (old == (unsigned)(gridDim.x - 1));
    }
    __syncthreads();
    if (!s_last) return;

    // ---- last block: epilogue over the 512 per-sample partials ----
    __threadfence();   // acquire

    const float focal_b = agld(ws + 0 * B_ + tid);
    const float inter   = agld(ws + 1 * B_ + tid);
    const float strict  = agld(ws + 2 * B_ + tid);
    const float copyf   = agld(ws + 3 * B_ + tid);
    const float nuv     = agld(ws + 4 * B_ + tid);
    const float crev    = agld(ws + 5 * B_ + tid);

    const float iou  = inter * (1.f / 4096.f);
    const float comb = 0.2f * strict + 0.8f * iou;
    const float divb = nuv * (1.f / 3969.f);

    volatile float* sp = &s_red[0][0];
    const float focal_s = block_sum(focal_b, sp, tid);
    const float comb_s  = block_sum(comb, sp, tid);
    const float iou_s   = block_sum(iou, sp, tid);
    const float copy_s  = block_sum(copyf, sp, tid);
    const float div_s   = block_sum(divb, sp, tid);
    const float cre_s   = block_sum(crev, sp, tid);

    if (tid == 0) {
        const float focal_loss        = focal_s / (512.f * 4096.f);
        const float comb_mean         = comb_s / 512.f;
        const float exact_count       = comb_s;
        const float exact_bonus       = fmaxf(-comb_mean * 5.f, -3.f);
        const float transform_penalty = (copy_s / 512.f) * 0.2f;
        const float creativity        = (cre_s / (512.f * 128.f)) * 0.15f;
        const float diversity         = (div_s / 512.f) * 0.02f;
        const float gcb               = comb_mean * 0.05f;  // grid factor == 1

        float total = focal_loss + transform_penalty + exact_bonus
                    - creativity - diversity - gcb;
        if (isnan(total) || isinf(total)) total = fminf(focal_loss, 10.f);

        out[0] = total;
        out[1] = focal_loss;
        out[2] = transform_penalty;
        out[3] = exact_bonus;
        out[4] = exact_count;
        out[5] = exact_count;   // combined_matches.sum() appears twice
        out[6] = iou_s / 512.f;
        out[7] = creativity;
        out[8] = diversity;
        out[9] = gcb;
    }
}

extern "C" void kernel_launch(void* const* d_in, const int* in_sizes, int n_in,
                              void* d_out, int out_size, void* d_ws, size_t ws_size,
                              hipStream_t stream)
{
    const float* pred  = (const float*)d_in[0];
    const int*   tgt   = (const int*)d_in[1];
    const int*   inp   = (const int*)d_in[2];
    const float* strat = (const float*)d_in[3];
    float* ws  = (float*)d_ws;
    float* out = (float*)d_out;
    unsigned int* ticket = (unsigned int*)(ws + 6 * B_);

    // ticket must be zero on every call (harness does not re-poison between replays)
    hipMemsetAsync(ticket, 0, sizeof(unsigned int), stream);
    hipLaunchKernelGGL(loss_all, dim3(B_), dim3(NT), 0, stream,
                       pred, tgt, inp, strat, ws, out, ticket);
}

// Round 4
// 45.325 us; speedup vs baseline: 1.0866x; 1.0866x over previous
//
#include <hip/hip_runtime.h>
#include <math.h>

#define B_    512
#define C_    10
#define HW_   4096
#define NT    512       // 8 waves/block, 1 block per sample, 8 px/thread
#define NBMP  313       // ceil(10^4 / 32) presence-bitmap words

__device__ __forceinline__ float wave_sum_f(float v) {
#pragma unroll
    for (int off = 32; off > 0; off >>= 1) v += __shfl_xor(v, off, 64);
    return v;
}
// Block-wide sum over NT threads; valid on tid==0 only.
__device__ __forceinline__ float block_sum(float v, volatile float* sp, int tid) {
    v = wave_sum_f(v);
    __syncthreads();
    if ((tid & 63) == 0) sp[tid >> 6] = v;
    __syncthreads();
    float s = 0.f;
    if (tid == 0) {
#pragma unroll
        for (int i = 0; i < NT / 64; ++i) s += sp[i];
    }
    return s;
}
__device__ __forceinline__ float agld(const float* p) {   // cross-XCD-safe load
    return __hip_atomic_load(p, __ATOMIC_RELAXED, __HIP_MEMORY_SCOPE_AGENT);
}

__global__ __launch_bounds__(NT, 4) void loss_all(
    const float* __restrict__ pred, const int* __restrict__ tgt,
    const int* __restrict__ inp, const float* __restrict__ strat,
    float* __restrict__ ws, float* __restrict__ out,
    unsigned int* __restrict__ ticket)
{
    const int b   = blockIdx.x;
    const int tid = threadIdx.x;

    __shared__ unsigned int s_pred32[HW_ / 4];   // packed pred_idx bytes
    __shared__ unsigned int s_bmp[NBMP];
    __shared__ float        s_red[8][5];
    __shared__ unsigned int s_cmask;
    __shared__ int          s_last;

    if (tid < NBMP) s_bmp[tid] = 0u;
    if (tid == 0) s_cmask = 0u;

    const float* pb = pred + (size_t)b * (C_ * HW_);

    float focal = 0.f;
    unsigned cmask = 0u;
    int eqc = 0, dfc = 0;

#pragma unroll
    for (int k = 0; k < 2; ++k) {
        const int p = (k * NT + tid) * 4;           // 4 px per round
        const int4 t4 = *(const int4*)(tgt + b * HW_ + p);
        const int4 i4 = *(const int4*)(inp + b * HW_ + p);
        float x[C_][4];
#pragma unroll
        for (int c = 0; c < C_; ++c) {
            const float4 v = *(const float4*)(pb + c * HW_ + p);
            x[c][0] = v.x; x[c][1] = v.y; x[c][2] = v.z; x[c][3] = v.w;
        }
        unsigned pack = 0u;
#pragma unroll
        for (int e = 0; e < 4; ++e) {
            const int t  = (e == 0) ? t4.x : (e == 1) ? t4.y : (e == 2) ? t4.z : t4.w;
            const int iv = (e == 0) ? i4.x : (e == 1) ? i4.y : (e == 2) ? i4.z : i4.w;
            cmask |= 1u << t;
            float mx = x[0][e]; int am = 0;
#pragma unroll
            for (int c = 1; c < C_; ++c)
                if (x[c][e] > mx) { mx = x[c][e]; am = c; }   // strict >: first max
            float se = 0.f, xt = 0.f;
#pragma unroll
            for (int c = 0; c < C_; ++c) {
                se += __expf(x[c][e] - mx);
                if (c == t) xt = x[c][e];
            }
            const float ce = (mx + __logf(se)) - xt;   // -log_softmax[target]
            const float pt = __expf(-ce);
            const float om = 1.f - pt;
            focal += om * om * ce;
            eqc += (am == t);
            dfc += (am != iv);
            pack |= (unsigned)am << (8 * e);
        }
        s_pred32[k * NT + tid] = pack;   // lane i -> dword i, conflict-free
    }

    float cre = 0.f;
    if (tid < 128) {
        const float sv = strat[b * 128 + tid];
        cre = 1.f / (1.f + __expf(-sv));
    }

    __syncthreads();   // s_pred32 complete, s_bmp zeroed

    // 2x2-window diversity over packed dwords: 63 rows x 16 dwords = 1008 slots
    for (int idx = tid; idx < 1008; idx += NT) {
        const int c4 = (idx & 15) << 2;            // 0,4,...,60
        const unsigned w0 = s_pred32[idx];
        const unsigned w1 = s_pred32[idx + 16];
        const unsigned n0 = (c4 < 60) ? s_pred32[idx + 1]  : 0u;
        const unsigned n1 = (c4 < 60) ? s_pred32[idx + 17] : 0u;
        const unsigned a0 =  w0        & 0xffu, a1 = (w0 >>  8) & 0xffu,
                       a2 = (w0 >> 16) & 0xffu, a3 = (w0 >> 24) & 0xffu,
                       a4 =  n0        & 0xffu;
        const unsigned b0 =  w1        & 0xffu, b1 = (w1 >>  8) & 0xffu,
                       b2 = (w1 >> 16) & 0xffu, b3 = (w1 >> 24) & 0xffu,
                       b4 =  n1        & 0xffu;
        unsigned code;
        code = a0 * 1000u + a1 * 100u + b0 * 10u + b1;
        atomicOr(&s_bmp[code >> 5], 1u << (code & 31u));
        code = a1 * 1000u + a2 * 100u + b1 * 10u + b2;
        atomicOr(&s_bmp[code >> 5], 1u << (code & 31u));
        code = a2 * 1000u + a3 * 100u + b2 * 10u + b3;
        atomicOr(&s_bmp[code >> 5], 1u << (code & 31u));
        if (c4 < 60) {
            code = a3 * 1000u + a4 * 100u + b3 * 10u + b4;
            atomicOr(&s_bmp[code >> 5], 1u << (code & 31u));
        }
    }
    __syncthreads();

    const int nu = (tid < NBMP) ? __popc(s_bmp[tid]) : 0;

    // per-sample reductions (8 waves): 5 shfl-reduces + colmask OR
    const float rf = wave_sum_f(focal);
    const float re = wave_sum_f((float)eqc);
    const float rd = wave_sum_f((float)dfc);
    const float rc = wave_sum_f(cre);
    const float rn = wave_sum_f((float)nu);
#pragma unroll
    for (int off = 32; off > 0; off >>= 1)
        cmask |= (unsigned)__shfl_xor((int)cmask, off, 64);

    const int wv = tid >> 6;
    if ((tid & 63) == 0) {
        s_red[wv][0] = rf; s_red[wv][1] = re; s_red[wv][2] = rd;
        s_red[wv][3] = rc; s_red[wv][4] = rn;
        atomicOr(&s_cmask, cmask);
    }
    __syncthreads();
    if (tid == 0) {
        float F = 0.f, E = 0.f, D = 0.f, CR = 0.f, NU = 0.f;
#pragma unroll
        for (int i = 0; i < 8; ++i) {
            F += s_red[i][0]; E += s_red[i][1]; D += s_red[i][2];
            CR += s_red[i][3]; NU += s_red[i][4];
        }
        const int uc = __popc(s_cmask);
        const float sw = (uc > 3) ? 1.2f : 1.0f;   // strategic weight
        ws[0 * B_ + b] = F * sw;
        ws[1 * B_ + b] = E;                               // intersection
        ws[2 * B_ + b] = (E == 4096.f) ? 1.f : 0.f;       // exact strict
        ws[3 * B_ + b] = (D == 0.f) ? 1.f : 0.f;          // copy flag
        ws[4 * B_ + b] = NU;                              // unique 2x2 codes
        ws[5 * B_ + b] = CR;                              // sigmoid sum
        __threadfence();                                  // release partials
        const unsigned old = atomicAdd(ticket, 1u);       // device-scope RMW
        s_last = (old == (unsigned)(gridDim.x - 1));
    }
    __syncthreads();
    if (!s_last) return;

    // ---- last block: epilogue over the 512 per-sample partials ----
    __threadfence();   // acquire

    const float focal_b = agld(ws + 0 * B_ + tid);
    const float inter   = agld(ws + 1 * B_ + tid);
    const float strict  = agld(ws + 2 * B_ + tid);
    const float copyf   = agld(ws + 3 * B_ + tid);
    const float nuv     = agld(ws + 4 * B_ + tid);
    const float crev    = agld(ws + 5 * B_ + tid);

    const float iou  = inter * (1.f / 4096.f);
    const float comb = 0.2f * strict + 0.8f * iou;
    const float divb = nuv * (1.f / 3969.f);

    volatile float* sp = &s_red[0][0];
    const float focal_s = block_sum(focal_b, sp, tid);
    const float comb_s  = block_sum(comb, sp, tid);
    const float iou_s   = block_sum(iou, sp, tid);
    const float copy_s  = block_sum(copyf, sp, tid);
    const float div_s   = block_sum(divb, sp, tid);
    const float cre_s   = block_sum(crev, sp, tid);

    if (tid == 0) {
        const float focal_loss        = focal_s / (512.f * 4096.f);
        const float comb_mean         = comb_s / 512.f;
        const float exact_count       = comb_s;
        const float exact_bonus       = fmaxf(-comb_mean * 5.f, -3.f);
        const float transform_penalty = (copy_s / 512.f) * 0.2f;
        const float creativity        = (cre_s / (512.f * 128.f)) * 0.15f;
        const float diversity         = (div_s / 512.f) * 0.02f;
        const float gcb               = comb_mean * 0.05f;  // grid factor == 1

        float total = focal_loss + transform_penalty + exact_bonus
                    - creativity - diversity - gcb;
        if (isnan(total) || isinf(total)) total = fminf(focal_loss, 10.f);

        out[0] = total;
        out[1] = focal_loss;
        out[2] = transform_penalty;
        out[3] = exact_bonus;
        out[4] = exact_count;
        out[5] = exact_count;   // combined_matches.sum() appears twice
        out[6] = iou_s / 512.f;
        out[7] = creativity;
        out[8] = diversity;
        out[9] = gcb;
    }
}

extern "C" void kernel_launch(void* const* d_in, const int* in_sizes, int n_in,
                              void* d_out, int out_size, void* d_ws, size_t ws_size,
                              hipStream_t stream)
{
    const float* pred  = (const float*)d_in[0];
    const int*   tgt   = (const int*)d_in[1];
    const int*   inp   = (const int*)d_in[2];
    const float* strat = (const float*)d_in[3];
    float* ws  = (float*)d_ws;
    float* out = (float*)d_out;
    unsigned int* ticket = (unsigned int*)(ws + 6 * B_);

    // ticket must be zero on every call (harness does not re-poison between replays)
    hipMemsetAsync(ticket, 0, sizeof(unsigned int), stream);
    hipLaunchKernelGGL(loss_all, dim3(B_), dim3(NT), 0, stream,
                       pred, tgt, inp, strat, ws, out, ticket);
}

// Round 5
// 28.906 us; speedup vs baseline: 1.7038x; 1.5680x over previous
//
#include <hip/hip_runtime.h>
#include <math.h>

#define B_    512
#define C_    10
#define HW_   4096
#define NT    512       // 8 waves/block, 1 block per sample, 8 px/thread
#define NBMP  313       // ceil(10^4 / 32) presence-bitmap words

__device__ __forceinline__ float wave_sum_f(float v) {
#pragma unroll
    for (int off = 32; off > 0; off >>= 1) v += __shfl_xor(v, off, 64);
    return v;
}
// Block-wide sum over NT threads; valid on tid==0 only.
__device__ __forceinline__ float block_sum(float v, volatile float* sp, int tid) {
    v = wave_sum_f(v);
    __syncthreads();
    if ((tid & 63) == 0) sp[tid >> 6] = v;
    __syncthreads();
    float s = 0.f;
    if (tid == 0) {
#pragma unroll
        for (int i = 0; i < NT / 64; ++i) s += sp[i];
    }
    return s;
}

// Process 4 pixels from float4 channel array X, targets T4, inputs I4.
// Accumulates focal/eqc/dfc/cmask; writes packed pred_idx to s_pred32[SLOT].
#define PROC4(X, T4, I4, SLOT)                                              \
    {                                                                       \
        unsigned pack = 0u;                                                 \
        _Pragma("unroll")                                                   \
        for (int e = 0; e < 4; ++e) {                                       \
            const int t  = (e==0)?T4.x:(e==1)?T4.y:(e==2)?T4.z:T4.w;        \
            const int iv = (e==0)?I4.x:(e==1)?I4.y:(e==2)?I4.z:I4.w;        \
            cmask |= 1u << t;                                               \
            float x0 = (e==0)?X[0].x:(e==1)?X[0].y:(e==2)?X[0].z:X[0].w;    \
            float mx = x0; int am = 0;                                      \
            float xs[C_];                                                   \
            xs[0] = x0;                                                     \
            _Pragma("unroll")                                               \
            for (int c = 1; c < C_; ++c) {                                  \
                const float xc = (e==0)?X[c].x:(e==1)?X[c].y:(e==2)?X[c].z:X[c].w; \
                xs[c] = xc;                                                 \
                if (xc > mx) { mx = xc; am = c; }  /* strict >: first max */\
            }                                                               \
            float se = 0.f, xt = 0.f;                                       \
            _Pragma("unroll")                                               \
            for (int c = 0; c < C_; ++c) {                                  \
                se += __expf(xs[c] - mx);                                   \
                if (c == t) xt = xs[c];                                     \
            }                                                               \
            const float ce = (mx + __logf(se)) - xt;                        \
            const float pt = __expf(-ce);                                   \
            const float om = 1.f - pt;                                      \
            focal += om * om * ce;                                          \
            eqc += (am == t);                                               \
            dfc += (am != iv);                                              \
            pack |= (unsigned)am << (8 * e);                                \
        }                                                                   \
        s_pred32[SLOT] = pack;                                              \
    }

__global__ __launch_bounds__(NT, 4) void loss_main(
    const float* __restrict__ pred, const int* __restrict__ tgt,
    const int* __restrict__ inp, const float* __restrict__ strat,
    float* __restrict__ ws)
{
    const int b   = blockIdx.x;
    const int tid = threadIdx.x;

    __shared__ unsigned int s_pred32[HW_ / 4];   // packed pred_idx bytes
    __shared__ unsigned int s_bmp[NBMP];
    __shared__ float        s_red[8][5];
    __shared__ unsigned int s_cmask;

    if (tid < NBMP) s_bmp[tid] = 0u;
    if (tid == 0) s_cmask = 0u;

    const float* pb = pred + (size_t)b * (C_ * HW_);
    const int p0 = tid * 4;            // first 4 px
    const int p1 = (NT + tid) * 4;     // second 4 px

    // ---- hoist ALL global loads: 20x dwordx4 + 4x int4 + strat ----
    float4 xa[C_], xb[C_];
#pragma unroll
    for (int c = 0; c < C_; ++c) xa[c] = *(const float4*)(pb + c * HW_ + p0);
#pragma unroll
    for (int c = 0; c < C_; ++c) xb[c] = *(const float4*)(pb + c * HW_ + p1);
    const int4 ta = *(const int4*)(tgt + b * HW_ + p0);
    const int4 tb4 = *(const int4*)(tgt + b * HW_ + p1);
    const int4 ia = *(const int4*)(inp + b * HW_ + p0);
    const int4 ib4 = *(const int4*)(inp + b * HW_ + p1);
    const float sv = (tid < 128) ? strat[b * 128 + tid] : 0.f;

    float focal = 0.f;
    unsigned cmask = 0u;
    int eqc = 0, dfc = 0;

    PROC4(xa, ta, ia, tid)
    PROC4(xb, tb4, ib4, NT + tid)

    const float cre = (tid < 128) ? 1.f / (1.f + __expf(-sv)) : 0.f;

    __syncthreads();   // s_pred32 complete, s_bmp zeroed

    // 2x2-window diversity over packed dwords: 63 rows x 16 dwords = 1008 slots
    for (int idx = tid; idx < 1008; idx += NT) {
        const int c4 = (idx & 15) << 2;            // 0,4,...,60
        const unsigned w0 = s_pred32[idx];
        const unsigned w1 = s_pred32[idx + 16];
        const unsigned n0 = (c4 < 60) ? s_pred32[idx + 1]  : 0u;
        const unsigned n1 = (c4 < 60) ? s_pred32[idx + 17] : 0u;
        const unsigned a0 =  w0        & 0xffu, a1 = (w0 >>  8) & 0xffu,
                       a2 = (w0 >> 16) & 0xffu, a3 = (w0 >> 24) & 0xffu,
                       a4 =  n0        & 0xffu;
        const unsigned b0 =  w1        & 0xffu, b1 = (w1 >>  8) & 0xffu,
                       b2 = (w1 >> 16) & 0xffu, b3 = (w1 >> 24) & 0xffu,
                       b4 =  n1        & 0xffu;
        unsigned code;
        code = a0 * 1000u + a1 * 100u + b0 * 10u + b1;
        atomicOr(&s_bmp[code >> 5], 1u << (code & 31u));
        code = a1 * 1000u + a2 * 100u + b1 * 10u + b2;
        atomicOr(&s_bmp[code >> 5], 1u << (code & 31u));
        code = a2 * 1000u + a3 * 100u + b2 * 10u + b3;
        atomicOr(&s_bmp[code >> 5], 1u << (code & 31u));
        if (c4 < 60) {
            code = a3 * 1000u + a4 * 100u + b3 * 10u + b4;
            atomicOr(&s_bmp[code >> 5], 1u << (code & 31u));
        }
    }
    __syncthreads();

    const int nu = (tid < NBMP) ? __popc(s_bmp[tid]) : 0;

    // per-sample reductions (8 waves): 5 shfl-reduces + colmask OR
    const float rf = wave_sum_f(focal);
    const float re = wave_sum_f((float)eqc);
    const float rd = wave_sum_f((float)dfc);
    const float rc = wave_sum_f(cre);
    const float rn = wave_sum_f((float)nu);
#pragma unroll
    for (int off = 32; off > 0; off >>= 1)
        cmask |= (unsigned)__shfl_xor((int)cmask, off, 64);

    const int wv = tid >> 6;
    if ((tid & 63) == 0) {
        s_red[wv][0] = rf; s_red[wv][1] = re; s_red[wv][2] = rd;
        s_red[wv][3] = rc; s_red[wv][4] = rn;
        atomicOr(&s_cmask, cmask);
    }
    __syncthreads();
    if (tid == 0) {
        float F = 0.f, E = 0.f, D = 0.f, CR = 0.f, NU = 0.f;
#pragma unroll
        for (int i = 0; i < 8; ++i) {
            F += s_red[i][0]; E += s_red[i][1]; D += s_red[i][2];
            CR += s_red[i][3]; NU += s_red[i][4];
        }
        const int uc = __popc(s_cmask);
        const float sw = (uc > 3) ? 1.2f : 1.0f;   // strategic weight
        ws[0 * B_ + b] = F * sw;
        ws[1 * B_ + b] = E;                               // intersection
        ws[2 * B_ + b] = (E == 4096.f) ? 1.f : 0.f;       // exact strict
        ws[3 * B_ + b] = (D == 0.f) ? 1.f : 0.f;          // copy flag
        ws[4 * B_ + b] = NU;                              // unique 2x2 codes
        ws[5 * B_ + b] = CR;                              // sigmoid sum
    }
}

__global__ __launch_bounds__(NT) void loss_final(
    const float* __restrict__ ws, float* __restrict__ out)
{
    const int tid = threadIdx.x;  // == b
    __shared__ float s_red[NT / 64];

    const float focal_b = ws[0 * B_ + tid];
    const float inter   = ws[1 * B_ + tid];
    const float strict  = ws[2 * B_ + tid];
    const float copyf   = ws[3 * B_ + tid];
    const float nu      = ws[4 * B_ + tid];
    const float cre     = ws[5 * B_ + tid];

    const float iou  = inter * (1.f / 4096.f);
    const float comb = 0.2f * strict + 0.8f * iou;
    const float divb = nu * (1.f / 3969.f);

    const float focal_s = block_sum(focal_b, s_red, tid);
    const float comb_s  = block_sum(comb, s_red, tid);
    const float iou_s   = block_sum(iou, s_red, tid);
    const float copy_s  = block_sum(copyf, s_red, tid);
    const float div_s   = block_sum(divb, s_red, tid);
    const float cre_s   = block_sum(cre, s_red, tid);

    if (tid == 0) {
        const float focal_loss        = focal_s / (512.f * 4096.f);
        const float comb_mean         = comb_s / 512.f;
        const float exact_count       = comb_s;
        const float exact_bonus       = fmaxf(-comb_mean * 5.f, -3.f);
        const float transform_penalty = (copy_s / 512.f) * 0.2f;
        const float creativity        = (cre_s / (512.f * 128.f)) * 0.15f;
        const float diversity         = (div_s / 512.f) * 0.02f;
        const float gcb               = comb_mean * 0.05f;  // grid factor == 1

        float total = focal_loss + transform_penalty + exact_bonus
                    - creativity - diversity - gcb;
        if (isnan(total) || isinf(total)) total = fminf(focal_loss, 10.f);

        out[0] = total;
        out[1] = focal_loss;
        out[2] = transform_penalty;
        out[3] = exact_bonus;
        out[4] = exact_count;
        out[5] = exact_count;   // combined_matches.sum() appears twice
        out[6] = iou_s / 512.f;
        out[7] = creativity;
        out[8] = diversity;
        out[9] = gcb;
    }
}

extern "C" void kernel_launch(void* const* d_in, const int* in_sizes, int n_in,
                              void* d_out, int out_size, void* d_ws, size_t ws_size,
                              hipStream_t stream)
{
    const float* pred  = (const float*)d_in[0];
    const int*   tgt   = (const int*)d_in[1];
    const int*   inp   = (const int*)d_in[2];
    const float* strat = (const float*)d_in[3];
    float* ws  = (float*)d_ws;
    float* out = (float*)d_out;

    hipLaunchKernelGGL(loss_main, dim3(B_), dim3(NT), 0, stream,
                       pred, tgt, inp, strat, ws);
    hipLaunchKernelGGL(loss_final, dim3(1), dim3(NT), 0, stream, ws, out);
}